// Round 1
// baseline (434.217 us; speedup 1.0000x reference)
//
#include <hip/hip_runtime.h>

#define NN 4096
#define IDX_CAP 512
#define SLOPE 0.2f

// ---- workspace layout (float offsets unless noted) ----
#define V_OFF     0                        // v1i,v2i,v1s,v2s : 4*128
#define C_OFF     512                      // 4 score constants
#define BT_OFF    516                      // b_total[128]
#define S_OFF     1024                     // s1i,s2i,s1s,s2s : 4*4096
#define HXI_OFF   32768                    // Ld@x   [4096,128]
#define HXS_OFF   (HXI_OFF + NN*128)       // Lu@x
#define UI_OFF    (HXS_OFF + NN*128)       // x@Wi0 + Hxi@Wi1
#define US_OFF    (UI_OFF + NN*128)        // x@Ws0 + Hxs@Ws1
#define XWH_OFF   (US_OFF + NN*128)        // x@Wh
#define OI_OFF    (XWH_OFF + NN*128)       // alpha_irr @ U_irr
#define OS_OFF    (OI_OFF + NN*128)        // alpha_sol @ U_sol
#define ZP_OFF    (OS_OFF + NN*128)        // P@xWh split-K partials: 8 * [4096,128]
#define WS_FLOATS (ZP_OFF + 8*NN*128)
#define IDX_BYTE_OFF ((size_t)WS_FLOATS * 4)                  // u16 idx lists: 2*4096*512
#define CNT_BYTE_OFF (IDX_BYTE_OFF + (size_t)2*NN*IDX_CAP*2)  // int counts: 2*4096
// total ws ≈ 38.2 MiB

// ---------------------------------------------------------------------------
// Prep: v-vectors so s1[i] = x[i,:]·v + c (x_irr never materialized), b_total.
__global__ __launch_bounds__(128) void k_prep(
    const float* __restrict__ Wi_w, const float* __restrict__ Wi_b,
    const float* __restrict__ Ws_w, const float* __restrict__ Ws_b,
    const float* __restrict__ Wh_b, const float* __restrict__ att_irr,
    const float* __restrict__ att_sol, float* __restrict__ ws) {
  const int t = threadIdx.x;  // one thread per input channel c
  float v1i = 0.f, v2i = 0.f, v1s = 0.f, v2s = 0.f;
  for (int j = 0; j < 2; ++j) {
    for (int o = 0; o < 128; ++o) {
      const float wi = Wi_w[j*16384 + t*128 + o];
      const float wv = Ws_w[j*16384 + t*128 + o];
      v1i += wi * att_irr[j*128 + o];
      v2i += wi * att_irr[256 + j*128 + o];
      v1s += wv * att_sol[j*128 + o];
      v2s += wv * att_sol[256 + j*128 + o];
    }
  }
  ws[V_OFF + t]       = v1i;
  ws[V_OFF + 128 + t] = v2i;
  ws[V_OFF + 256 + t] = v1s;
  ws[V_OFF + 384 + t] = v2s;
  ws[BT_OFF + t] = Wi_b[t] + Wi_b[128 + t] + Ws_b[t] + Ws_b[128 + t] + Wh_b[t];
  if (t < 4) {
    const float* bb = (t < 2) ? Wi_b : Ws_b;
    const float* aa = ((t < 2) ? att_irr : att_sol) + ((t & 1) ? 256 : 0);
    float c = 0.f;
    for (int k = 0; k < 256; ++k) c += bb[k] * aa[k];
    ws[C_OFF + t] = c;   // c1i, c2i, c1s, c2s
  }
}

// ---------------------------------------------------------------------------
// Attention scores: one wave per row, 4 dots against the v-vectors.
__global__ __launch_bounds__(256) void k_scores(const float* __restrict__ x,
                                                float* __restrict__ ws) {
  const int wave = threadIdx.x >> 6, lane = threadIdx.x & 63;
  const int row = blockIdx.x * 4 + wave;
  const float* v = ws + V_OFF;
  const float x0 = x[row*128 + lane];
  const float x1 = x[row*128 + 64 + lane];
  float p0 = x0 * v[lane]       + x1 * v[64 + lane];
  float p1 = x0 * v[128 + lane] + x1 * v[192 + lane];
  float p2 = x0 * v[256 + lane] + x1 * v[320 + lane];
  float p3 = x0 * v[384 + lane] + x1 * v[448 + lane];
  #pragma unroll
  for (int off = 32; off; off >>= 1) {
    p0 += __shfl_down(p0, off);
    p1 += __shfl_down(p1, off);
    p2 += __shfl_down(p2, off);
    p3 += __shfl_down(p3, off);
  }
  if (lane == 0) {
    ws[S_OFF + row]          = p0 + ws[C_OFF + 0];  // s1_irr
    ws[S_OFF + NN + row]     = p1 + ws[C_OFF + 1];  // s2_irr
    ws[S_OFF + 2*NN + row]   = p2 + ws[C_OFF + 2];  // s1_sol
    ws[S_OFF + 3*NN + row]   = p3 + ws[C_OFF + 3];  // s2_sol
  }
}

// ---------------------------------------------------------------------------
// Sparse row pass: Hx = L@x per row via ballot-compaction; also emits the
// nonzero-index list (u16) reused by k_attn so Lu/Ld are scanned only once there.
__global__ __launch_bounds__(128) void k_spmm_emit(
    const float* __restrict__ Ld, const float* __restrict__ Lu,
    const float* __restrict__ x, float* __restrict__ ws,
    unsigned short* __restrict__ idxbuf, int* __restrict__ cntbuf) {
  const int row = blockIdx.x & (NN - 1);
  const int br  = blockIdx.x >> 12;            // 0: irr/Ld, 1: sol/Lu
  const float* __restrict__ Lrow = (br ? Lu : Ld) + (size_t)row * NN;
  float* __restrict__ Hx = ws + (br ? HXS_OFF : HXI_OFF);
  unsigned short* __restrict__ idx = idxbuf + (size_t)(br*NN + row) * IDX_CAP;
  const int t = threadIdx.x;

  __shared__ int   ls_cnt;
  __shared__ int   ls_j[1024];
  __shared__ float ls_v[1024];

  float acc = 0.f;
  int done = 0;
  for (int k0 = 0; k0 < NN; k0 += 1024) {
    if (t == 0) ls_cnt = 0;
    __syncthreads();
    #pragma unroll
    for (int it = 0; it < 8; ++it) {
      const int j = k0 + it*128 + t;
      const float v = Lrow[j];
      const unsigned long long m = __ballot(v != 0.f);
      const int lane = t & 63;
      int base = 0;
      if (lane == 0 && m) base = atomicAdd(&ls_cnt, (int)__popcll(m));
      base = __shfl(base, 0);
      if (v != 0.f) {
        const int pos = base + (int)__popcll(m & ((1ull << lane) - 1ull));
        ls_j[pos] = j;
        ls_v[pos] = v;
      }
    }
    __syncthreads();
    const int m = ls_cnt;
    for (int p = t; p < m; p += 128) {
      const int g = done + p;
      if (g < IDX_CAP) idx[g] = (unsigned short)ls_j[p];
    }
    int p = 0;
    for (; p + 4 <= m; p += 4) {       // unroll 4: four independent L2 gathers in flight
      const int j0 = ls_j[p], j1 = ls_j[p+1], j2 = ls_j[p+2], j3 = ls_j[p+3];
      const float v0 = ls_v[p], v1 = ls_v[p+1], v2 = ls_v[p+2], v3 = ls_v[p+3];
      const float g0 = x[j0*128 + t], g1 = x[j1*128 + t];
      const float g2 = x[j2*128 + t], g3 = x[j3*128 + t];
      acc += v0*g0; acc += v1*g1; acc += v2*g2; acc += v3*g3;
    }
    for (; p < m; ++p) acc += ls_v[p] * x[ls_j[p]*128 + t];
    done += m;
    __syncthreads();
  }
  Hx[row*128 + t] = acc;
  if (t == 0) cntbuf[br*NN + row] = done;
}

// ---------------------------------------------------------------------------
// Small GEMMs: U_irr = x@Wi0 + Hxi@Wi1 ; U_sol = x@Ws0 + Hxs@Ws1 ; xWh = x@Wh.
// BM=32, BN=128, BK=32, 256 threads, thread tile 2x8.
__global__ __launch_bounds__(256) void k_ugemm(
    const float* __restrict__ x, const float* __restrict__ Wi_w,
    const float* __restrict__ Ws_w, const float* __restrict__ Wh_w,
    float* __restrict__ ws) {
  const int rb = blockIdx.x;       // 128 row-blocks of 32
  const int sel = blockIdx.y;      // 0:U_irr 1:U_sol 2:xWh
  const float* A[2]; const float* W[2]; int npass; float* out;
  if (sel == 0)      { A[0]=x; W[0]=Wi_w; A[1]=ws+HXI_OFF; W[1]=Wi_w+16384; npass=2; out=ws+UI_OFF; }
  else if (sel == 1) { A[0]=x; W[0]=Ws_w; A[1]=ws+HXS_OFF; W[1]=Ws_w+16384; npass=2; out=ws+US_OFF; }
  else               { A[0]=x; W[0]=Wh_w; A[1]=nullptr;    W[1]=nullptr;    npass=1; out=ws+XWH_OFF; }

  __shared__ __align__(16) float At[32][33];
  __shared__ __align__(16) float Wt[32][132];
  const int t = threadIdx.x;
  const int rg = t >> 4, cg = t & 15;  // 16 row-groups x 2 rows, 16 col-groups x 8 cols
  const int r0 = rb * 32;
  float acc[2][8];
  #pragma unroll
  for (int i = 0; i < 2; ++i)
    #pragma unroll
    for (int j = 0; j < 8; ++j) acc[i][j] = 0.f;

  for (int ps = 0; ps < npass; ++ps) {
    const float* __restrict__ Ap = A[ps];
    const float* __restrict__ Wp = W[ps];
    for (int k0 = 0; k0 < 128; k0 += 32) {
      __syncthreads();
      { // stage A: 32x32, one float4 per thread
        const int row = t >> 3, kq = t & 7;
        const float4 av = *(const float4*)&Ap[(r0 + row)*128 + k0 + kq*4];
        At[row][kq*4+0] = av.x; At[row][kq*4+1] = av.y;
        At[row][kq*4+2] = av.z; At[row][kq*4+3] = av.w;
      }
      #pragma unroll
      for (int l = 0; l < 4; ++l) { // stage W: 32x128
        const int idx = t + l*256;
        const int kr = idx >> 5, c4 = idx & 31;
        const float4 wv = *(const float4*)&Wp[(k0 + kr)*128 + c4*4];
        Wt[kr][c4*4+0] = wv.x; Wt[kr][c4*4+1] = wv.y;
        Wt[kr][c4*4+2] = wv.z; Wt[kr][c4*4+3] = wv.w;
      }
      __syncthreads();
      #pragma unroll
      for (int k = 0; k < 32; ++k) {
        const float a0 = At[rg*2 + 0][k];
        const float a1 = At[rg*2 + 1][k];
        const float4 b0 = *(const float4*)&Wt[k][cg*8];
        const float4 b1 = *(const float4*)&Wt[k][cg*8 + 4];
        acc[0][0] += a0*b0.x; acc[0][1] += a0*b0.y; acc[0][2] += a0*b0.z; acc[0][3] += a0*b0.w;
        acc[0][4] += a0*b1.x; acc[0][5] += a0*b1.y; acc[0][6] += a0*b1.z; acc[0][7] += a0*b1.w;
        acc[1][0] += a1*b0.x; acc[1][1] += a1*b0.y; acc[1][2] += a1*b0.z; acc[1][3] += a1*b0.w;
        acc[1][4] += a1*b1.x; acc[1][5] += a1*b1.y; acc[1][6] += a1*b1.z; acc[1][7] += a1*b1.w;
      }
    }
  }
  #pragma unroll
  for (int i = 0; i < 2; ++i) {
    const int r = r0 + rg*2 + i;
    #pragma unroll
    for (int j = 0; j < 8; ++j) out[r*128 + cg*8 + j] = acc[i][j];
  }
}

// ---------------------------------------------------------------------------
// Dense P @ xWh, split-K=8 into partial buffers. BM=64, BN=128, BK=32,
// 256 threads, thread tile 4x8.
__global__ __launch_bounds__(256) void k_pgemm(const float* __restrict__ P,
                                               const float* __restrict__ ws,
                                               float* __restrict__ zpart) {
  const int rbl = blockIdx.x;   // 64 row-blocks of 64
  const int kz  = blockIdx.y;   // 8 K-splits of 512
  const float* __restrict__ Xw = ws + XWH_OFF;

  __shared__ __align__(16) float Pt[64][33];
  __shared__ __align__(16) float Xt[32][132];
  const int t = threadIdx.x;
  const int rg = t >> 4, cg = t & 15;   // 16 x 4 rows, 16 x 8 cols
  const int r0 = rbl * 64;
  const int kbase = kz * 512;
  float acc[4][8];
  #pragma unroll
  for (int i = 0; i < 4; ++i)
    #pragma unroll
    for (int j = 0; j < 8; ++j) acc[i][j] = 0.f;

  for (int k0 = kbase; k0 < kbase + 512; k0 += 32) {
    __syncthreads();
    #pragma unroll
    for (int l = 0; l < 2; ++l) { // stage P: 64x32
      const int idx = t + l*256;
      const int row = idx >> 3, kq = idx & 7;
      const float4 pv = *(const float4*)&P[(size_t)(r0 + row)*NN + k0 + kq*4];
      Pt[row][kq*4+0] = pv.x; Pt[row][kq*4+1] = pv.y;
      Pt[row][kq*4+2] = pv.z; Pt[row][kq*4+3] = pv.w;
    }
    #pragma unroll
    for (int l = 0; l < 4; ++l) { // stage xWh: 32x128
      const int idx = t + l*256;
      const int kr = idx >> 5, c4 = idx & 31;
      const float4 xv = *(const float4*)&Xw[(k0 + kr)*128 + c4*4];
      Xt[kr][c4*4+0] = xv.x; Xt[kr][c4*4+1] = xv.y;
      Xt[kr][c4*4+2] = xv.z; Xt[kr][c4*4+3] = xv.w;
    }
    __syncthreads();
    #pragma unroll
    for (int k = 0; k < 32; ++k) {
      const float a0 = Pt[rg*4 + 0][k];
      const float a1 = Pt[rg*4 + 1][k];
      const float a2 = Pt[rg*4 + 2][k];
      const float a3 = Pt[rg*4 + 3][k];
      const float4 b0 = *(const float4*)&Xt[k][cg*8];
      const float4 b1 = *(const float4*)&Xt[k][cg*8 + 4];
      acc[0][0] += a0*b0.x; acc[0][1] += a0*b0.y; acc[0][2] += a0*b0.z; acc[0][3] += a0*b0.w;
      acc[0][4] += a0*b1.x; acc[0][5] += a0*b1.y; acc[0][6] += a0*b1.z; acc[0][7] += a0*b1.w;
      acc[1][0] += a1*b0.x; acc[1][1] += a1*b0.y; acc[1][2] += a1*b0.z; acc[1][3] += a1*b0.w;
      acc[1][4] += a1*b1.x; acc[1][5] += a1*b1.y; acc[1][6] += a1*b1.z; acc[1][7] += a1*b1.w;
      acc[2][0] += a2*b0.x; acc[2][1] += a2*b0.y; acc[2][2] += a2*b0.z; acc[2][3] += a2*b0.w;
      acc[2][4] += a2*b1.x; acc[2][5] += a2*b1.y; acc[2][6] += a2*b1.z; acc[2][7] += a2*b1.w;
      acc[3][0] += a3*b0.x; acc[3][1] += a3*b0.y; acc[3][2] += a3*b0.z; acc[3][3] += a3*b0.w;
      acc[3][4] += a3*b1.x; acc[3][5] += a3*b1.y; acc[3][6] += a3*b1.z; acc[3][7] += a3*b1.w;
    }
  }
  float* __restrict__ zp = zpart + (size_t)kz * NN * 128;
  #pragma unroll
  for (int i = 0; i < 4; ++i) {
    const int r = r0 + rg*4 + i;
    #pragma unroll
    for (int j = 0; j < 8; ++j) zp[r*128 + cg*8 + j] = acc[i][j];
  }
}

// ---------------------------------------------------------------------------
// Masked-softmax attention, one block per (row, branch). Uses the u16 index
// lists: O[i,:] = (sum_j e_j * U[j,:]) / (sum_j e_j), e_j = exp(leaky(s1+s2[j])).
// Masked entries underflow to exactly 0 in the reference, so skipping is exact.
__global__ __launch_bounds__(256) void k_attn(
    const float* __restrict__ Ld, const float* __restrict__ Lu,
    float* __restrict__ ws, const unsigned short* __restrict__ idxbuf,
    const int* __restrict__ cntbuf) {
  const int row = blockIdx.x & (NN - 1);
  const int br  = blockIdx.x >> 12;
  const float* __restrict__ U = ws + (br ? US_OFF : UI_OFF);
  float* __restrict__ O = ws + (br ? OS_OFF : OI_OFF);
  const float s1 = ws[S_OFF + (br ? 2*NN : 0) + row];
  const float* __restrict__ s2a = ws + S_OFF + (br ? 3*NN : NN);
  const int cnt = cntbuf[br*NN + row];
  const int t = threadIdx.x;
  const int col = t & 127;
  const int half = t >> 7;

  __shared__ int   jl[IDX_CAP];
  __shared__ float el[IDX_CAP];
  __shared__ float red[256];
  __shared__ float dsh[2];

  float acc = 0.f;
  if (cnt > 0 && cnt <= IDX_CAP) {
    const unsigned short* __restrict__ idx = idxbuf + (size_t)(br*NN + row) * IDX_CAP;
    float dpart = 0.f;
    for (int p = t; p < cnt; p += 256) {
      const int j = idx[p];
      const float sc = s1 + s2a[j];
      const float e = expf(sc >= 0.f ? sc : SLOPE * sc);
      jl[p] = j; el[p] = e; dpart += e;
    }
    red[t] = dpart;
    __syncthreads();
    if (t < 128) red[t] += red[t + 128];
    __syncthreads();
    if (t < 64) {
      float v = red[t] + red[t + 64];
      #pragma unroll
      for (int off = 32; off; off >>= 1) v += __shfl_down(v, off);
      if (t == 0) dsh[0] = v;
    }
    __syncthreads();
    const float den = dsh[0];
    int p = half;                       // halves interleave over the list
    for (; p + 8 <= cnt; p += 8) {
      const int j0 = jl[p], j1 = jl[p+2], j2 = jl[p+4], j3 = jl[p+6];
      const float e0 = el[p], e1 = el[p+2], e2 = el[p+4], e3 = el[p+6];
      const float g0 = U[j0*128 + col], g1 = U[j1*128 + col];
      const float g2 = U[j2*128 + col], g3 = U[j3*128 + col];
      acc += e0*g0; acc += e1*g1; acc += e2*g2; acc += e3*g3;
    }
    for (; p < cnt; p += 2) acc += el[p] * U[jl[p]*128 + col];
    red[t] = acc;
    __syncthreads();
    if (t < 128) O[row*128 + t] = (red[t] + red[t + 128]) / den;
  } else if (cnt == 0) {
    // all-masked row -> reference softmax is uniform 1/N
    for (int j = half; j < NN; j += 2) acc += U[j*128 + col];
    red[t] = acc;
    __syncthreads();
    if (t < 128) O[row*128 + t] = (red[t] + red[t + 128]) * (1.f / NN);
  } else {
    // overflowed index cap (statistically impossible at 5% density): dense rescan
    const float* __restrict__ Lrow = (br ? Lu : Ld) + (size_t)row * NN;
    float dpart = 0.f;
    for (int j = half; j < NN; j += 2) {
      const float v = Lrow[j];
      if (v != 0.f) {
        const float sc = s1 + s2a[j];
        const float e = expf(sc >= 0.f ? sc : SLOPE * sc);
        if (col == 0) dpart += e;
        acc += e * U[j*128 + col];
      }
    }
    if (col == 0) dsh[half] = dpart;
    red[t] = acc;
    __syncthreads();
    const float den = dsh[0] + dsh[1];
    if (t < 128) O[row*128 + t] = (red[t] + red[t + 128]) / den;
  }
}

// ---------------------------------------------------------------------------
// z = O_irr + O_sol + sum_k zpart[k] + b_total
__global__ __launch_bounds__(256) void k_combine(const float* __restrict__ ws,
                                                 float* __restrict__ z) {
  const int i = blockIdx.x * 256 + threadIdx.x;
  const int col = i & 127;
  float acc = ws[BT_OFF + col] + ws[OI_OFF + i] + ws[OS_OFF + i];
  #pragma unroll
  for (int kz = 0; kz < 8; ++kz) acc += ws[ZP_OFF + kz*NN*128 + i];
  z[i] = acc;
}

// ---------------------------------------------------------------------------
extern "C" void kernel_launch(void* const* d_in, const int* in_sizes, int n_in,
                              void* d_out, int out_size, void* d_ws, size_t ws_size,
                              hipStream_t stream) {
  const float* x       = (const float*)d_in[0];
  const float* Lu      = (const float*)d_in[1];
  const float* Ld      = (const float*)d_in[2];
  const float* P       = (const float*)d_in[3];
  const float* Wi_w    = (const float*)d_in[4];
  const float* Wi_b    = (const float*)d_in[5];
  const float* Ws_w    = (const float*)d_in[6];
  const float* Ws_b    = (const float*)d_in[7];
  const float* Wh_w    = (const float*)d_in[8];
  const float* Wh_b    = (const float*)d_in[9];
  const float* att_irr = (const float*)d_in[10];
  const float* att_sol = (const float*)d_in[11];
  float* z  = (float*)d_out;
  float* ws = (float*)d_ws;
  unsigned short* idxbuf = (unsigned short*)((char*)d_ws + IDX_BYTE_OFF);
  int*            cntbuf = (int*)((char*)d_ws + CNT_BYTE_OFF);

  k_prep<<<1, 128, 0, stream>>>(Wi_w, Wi_b, Ws_w, Ws_b, Wh_b, att_irr, att_sol, ws);
  k_scores<<<1024, 256, 0, stream>>>(x, ws);
  k_spmm_emit<<<2 * NN, 128, 0, stream>>>(Ld, Lu, x, ws, idxbuf, cntbuf);
  {
    dim3 g(128, 3);
    k_ugemm<<<g, 256, 0, stream>>>(x, Wi_w, Ws_w, Wh_w, ws);
  }
  {
    dim3 g(64, 8);
    k_pgemm<<<g, 256, 0, stream>>>(P, ws, ws + ZP_OFF);
  }
  k_attn<<<2 * NN, 256, 0, stream>>>(Ld, Lu, ws, idxbuf, cntbuf);
  k_combine<<<NN * 128 / 256, 256, 0, stream>>>(ws, z);
}

// Round 2
// 400.007 us; speedup vs baseline: 1.0855x; 1.0855x over previous
//
#include <hip/hip_runtime.h>

#define NN 4096
#define IDX_CAP 512
#define SLOPE 0.2f

// ---- workspace layout (float offsets unless noted) ----
#define V_OFF     0                        // v1i,v2i,v1s,v2s : 4*128
#define C_OFF     512                      // 4 score constants
#define BT_OFF    516                      // b_total[128]
#define S_OFF     1024                     // s1i,s2i,s1s,s2s : 4*4096
#define HXI_OFF   32768                    // Ld@x   [4096,128]
#define HXS_OFF   (HXI_OFF + NN*128)       // Lu@x
#define UI_OFF    (HXS_OFF + NN*128)       // x@Wi0 + Hxi@Wi1
#define US_OFF    (UI_OFF + NN*128)        // x@Ws0 + Hxs@Ws1
#define XWH_OFF   (US_OFF + NN*128)        // x@Wh
#define OI_OFF    (XWH_OFF + NN*128)       // alpha_irr @ U_irr
#define OS_OFF    (OI_OFF + NN*128)        // alpha_sol @ U_sol
#define ZP_OFF    (OS_OFF + NN*128)        // P@xWh split-K partials: 8 * [4096,128]
#define WS_FLOATS (ZP_OFF + 8*NN*128)
#define IDX_BYTE_OFF ((size_t)WS_FLOATS * 4)                  // u16 idx lists: 2*4096*512
#define CNT_BYTE_OFF (IDX_BYTE_OFF + (size_t)2*NN*IDX_CAP*2)  // int counts: 2*4096
// total ws ≈ 38.2 MiB

// ---------------------------------------------------------------------------
// Prep: v-vectors so s1[i] = x[i,:]·v + c (x_irr never materialized), b_total.
__global__ __launch_bounds__(128) void k_prep(
    const float* __restrict__ Wi_w, const float* __restrict__ Wi_b,
    const float* __restrict__ Ws_w, const float* __restrict__ Ws_b,
    const float* __restrict__ Wh_b, const float* __restrict__ att_irr,
    const float* __restrict__ att_sol, float* __restrict__ ws) {
  const int t = threadIdx.x;  // one thread per input channel c
  float v1i = 0.f, v2i = 0.f, v1s = 0.f, v2s = 0.f;
  for (int j = 0; j < 2; ++j) {
    for (int o = 0; o < 128; ++o) {
      const float wi = Wi_w[j*16384 + t*128 + o];
      const float wv = Ws_w[j*16384 + t*128 + o];
      v1i += wi * att_irr[j*128 + o];
      v2i += wi * att_irr[256 + j*128 + o];
      v1s += wv * att_sol[j*128 + o];
      v2s += wv * att_sol[256 + j*128 + o];
    }
  }
  ws[V_OFF + t]       = v1i;
  ws[V_OFF + 128 + t] = v2i;
  ws[V_OFF + 256 + t] = v1s;
  ws[V_OFF + 384 + t] = v2s;
  ws[BT_OFF + t] = Wi_b[t] + Wi_b[128 + t] + Ws_b[t] + Ws_b[128 + t] + Wh_b[t];
  if (t < 4) {
    const float* bb = (t < 2) ? Wi_b : Ws_b;
    const float* aa = ((t < 2) ? att_irr : att_sol) + ((t & 1) ? 256 : 0);
    float c = 0.f;
    for (int k = 0; k < 256; ++k) c += bb[k] * aa[k];
    ws[C_OFF + t] = c;   // c1i, c2i, c1s, c2s
  }
}

// ---------------------------------------------------------------------------
// Attention scores: one wave per row, 4 dots against the v-vectors.
__global__ __launch_bounds__(256) void k_scores(const float* __restrict__ x,
                                                float* __restrict__ ws) {
  const int wave = threadIdx.x >> 6, lane = threadIdx.x & 63;
  const int row = blockIdx.x * 4 + wave;
  const float* v = ws + V_OFF;
  const float x0 = x[row*128 + lane];
  const float x1 = x[row*128 + 64 + lane];
  float p0 = x0 * v[lane]       + x1 * v[64 + lane];
  float p1 = x0 * v[128 + lane] + x1 * v[192 + lane];
  float p2 = x0 * v[256 + lane] + x1 * v[320 + lane];
  float p3 = x0 * v[384 + lane] + x1 * v[448 + lane];
  #pragma unroll
  for (int off = 32; off; off >>= 1) {
    p0 += __shfl_down(p0, off);
    p1 += __shfl_down(p1, off);
    p2 += __shfl_down(p2, off);
    p3 += __shfl_down(p3, off);
  }
  if (lane == 0) {
    ws[S_OFF + row]          = p0 + ws[C_OFF + 0];  // s1_irr
    ws[S_OFF + NN + row]     = p1 + ws[C_OFF + 1];  // s2_irr
    ws[S_OFF + 2*NN + row]   = p2 + ws[C_OFF + 2];  // s1_sol
    ws[S_OFF + 3*NN + row]   = p3 + ws[C_OFF + 3];  // s2_sol
  }
}

// ---------------------------------------------------------------------------
// Sparse row pass v2: 256 threads / 4 waves per (row, branch).
// Scan: 4 coalesced float4 loads per thread, single ballot-compaction, ONE
// barrier. Gather: waves interleave over the nnz list (16 independent 512B
// L2 gathers in flight per block vs 4 before), lane covers 2 cols via float2.
__global__ __launch_bounds__(256) void k_spmm_emit(
    const float* __restrict__ Ld, const float* __restrict__ Lu,
    const float* __restrict__ x, float* __restrict__ ws,
    unsigned short* __restrict__ idxbuf, int* __restrict__ cntbuf) {
  const int row = blockIdx.x & (NN - 1);
  const int br  = blockIdx.x >> 12;            // 0: irr/Ld, 1: sol/Lu
  const float* __restrict__ Lrow = (br ? Lu : Ld) + (size_t)row * NN;
  float* __restrict__ Hx = ws + (br ? HXS_OFF : HXI_OFF);
  unsigned short* __restrict__ idxg = idxbuf + (size_t)(br*NN + row) * IDX_CAP;
  const float2* __restrict__ x2 = (const float2*)x;
  const int t = threadIdx.x;
  const int w = t >> 6, lane = t & 63;

  __shared__ int   cnt;
  __shared__ int   jl[IDX_CAP];
  __shared__ float vl[IDX_CAP];
  __shared__ float red[4][128];

  if (t == 0) cnt = 0;
  __syncthreads();

  // ---- scan 16 KB row: 4 float4 per thread, ballot-compact per component ----
  const float4* __restrict__ Lrow4 = (const float4*)Lrow;
  float4 lv[4];
  #pragma unroll
  for (int i = 0; i < 4; ++i) lv[i] = Lrow4[i*256 + t];
  #pragma unroll
  for (int i = 0; i < 4; ++i) {
    #pragma unroll
    for (int c = 0; c < 4; ++c) {
      const float v = (&lv[i].x)[c];
      const unsigned long long m = __ballot(v != 0.f);
      int base = 0;
      if (lane == 0 && m) base = atomicAdd(&cnt, (int)__popcll(m));
      base = __shfl(base, 0);
      if (v != 0.f) {
        const int pos = base + (int)__popcll(m & ((1ull << lane) - 1ull));
        if (pos < IDX_CAP) { jl[pos] = (i*256 + t)*4 + c; vl[pos] = v; }
      }
    }
  }
  __syncthreads();
  const int m = cnt;

  // emit index list for k_attn reuse
  for (int p = t; p < m && p < IDX_CAP; p += 256) idxg[p] = (unsigned short)jl[p];
  if (t == 0) cntbuf[br*NN + row] = m;

  float acc0 = 0.f, acc1 = 0.f;
  if (m <= IDX_CAP) {
    // ---- gather: wave w takes p = w, w+4, ... ; unroll 4 -> stride 16 ----
    int p = w;
    for (; p + 12 < m; p += 16) {
      const int j0 = jl[p], j1 = jl[p+4], j2 = jl[p+8], j3 = jl[p+12];
      const float v0 = vl[p], v1 = vl[p+4], v2 = vl[p+8], v3 = vl[p+12];
      const float2 g0 = x2[j0*64 + lane];
      const float2 g1 = x2[j1*64 + lane];
      const float2 g2 = x2[j2*64 + lane];
      const float2 g3 = x2[j3*64 + lane];
      acc0 += v0*g0.x; acc1 += v0*g0.y;
      acc0 += v1*g1.x; acc1 += v1*g1.y;
      acc0 += v2*g2.x; acc1 += v2*g2.y;
      acc0 += v3*g3.x; acc1 += v3*g3.y;
    }
    for (; p < m; p += 4) {
      const int j = jl[p]; const float v = vl[p];
      const float2 g = x2[j*64 + lane];
      acc0 += v*g.x; acc1 += v*g.y;
    }
  } else {
    // overflow fallback (statistically impossible at 5%): dense rescan, wave quarter
    for (int j = w*1024; j < (w+1)*1024; ++j) {
      const float v = Lrow[j];
      if (v != 0.f) {
        const float2 g = x2[j*64 + lane];
        acc0 += v*g.x; acc1 += v*g.y;
      }
    }
  }
  red[w][lane*2]     = acc0;
  red[w][lane*2 + 1] = acc1;
  __syncthreads();
  if (t < 128)
    Hx[row*128 + t] = red[0][t] + red[1][t] + red[2][t] + red[3][t];
}

// ---------------------------------------------------------------------------
// Small GEMMs: U_irr = x@Wi0 + Hxi@Wi1 ; U_sol = x@Ws0 + Hxs@Ws1 ; xWh = x@Wh.
// BM=32, BN=128, BK=32, 256 threads, thread tile 2x8.
__global__ __launch_bounds__(256) void k_ugemm(
    const float* __restrict__ x, const float* __restrict__ Wi_w,
    const float* __restrict__ Ws_w, const float* __restrict__ Wh_w,
    float* __restrict__ ws) {
  const int rb = blockIdx.x;       // 128 row-blocks of 32
  const int sel = blockIdx.y;      // 0:U_irr 1:U_sol 2:xWh
  const float* A[2]; const float* W[2]; int npass; float* out;
  if (sel == 0)      { A[0]=x; W[0]=Wi_w; A[1]=ws+HXI_OFF; W[1]=Wi_w+16384; npass=2; out=ws+UI_OFF; }
  else if (sel == 1) { A[0]=x; W[0]=Ws_w; A[1]=ws+HXS_OFF; W[1]=Ws_w+16384; npass=2; out=ws+US_OFF; }
  else               { A[0]=x; W[0]=Wh_w; A[1]=nullptr;    W[1]=nullptr;    npass=1; out=ws+XWH_OFF; }

  __shared__ __align__(16) float At[32][33];
  __shared__ __align__(16) float Wt[32][132];
  const int t = threadIdx.x;
  const int rg = t >> 4, cg = t & 15;  // 16 row-groups x 2 rows, 16 col-groups x 8 cols
  const int r0 = rb * 32;
  float acc[2][8];
  #pragma unroll
  for (int i = 0; i < 2; ++i)
    #pragma unroll
    for (int j = 0; j < 8; ++j) acc[i][j] = 0.f;

  for (int ps = 0; ps < npass; ++ps) {
    const float* __restrict__ Ap = A[ps];
    const float* __restrict__ Wp = W[ps];
    for (int k0 = 0; k0 < 128; k0 += 32) {
      __syncthreads();
      { // stage A: 32x32, one float4 per thread
        const int row = t >> 3, kq = t & 7;
        const float4 av = *(const float4*)&Ap[(r0 + row)*128 + k0 + kq*4];
        At[row][kq*4+0] = av.x; At[row][kq*4+1] = av.y;
        At[row][kq*4+2] = av.z; At[row][kq*4+3] = av.w;
      }
      #pragma unroll
      for (int l = 0; l < 4; ++l) { // stage W: 32x128
        const int idx = t + l*256;
        const int kr = idx >> 5, c4 = idx & 31;
        const float4 wv = *(const float4*)&Wp[(k0 + kr)*128 + c4*4];
        Wt[kr][c4*4+0] = wv.x; Wt[kr][c4*4+1] = wv.y;
        Wt[kr][c4*4+2] = wv.z; Wt[kr][c4*4+3] = wv.w;
      }
      __syncthreads();
      #pragma unroll
      for (int k = 0; k < 32; ++k) {
        const float a0 = At[rg*2 + 0][k];
        const float a1 = At[rg*2 + 1][k];
        const float4 b0 = *(const float4*)&Wt[k][cg*8];
        const float4 b1 = *(const float4*)&Wt[k][cg*8 + 4];
        acc[0][0] += a0*b0.x; acc[0][1] += a0*b0.y; acc[0][2] += a0*b0.z; acc[0][3] += a0*b0.w;
        acc[0][4] += a0*b1.x; acc[0][5] += a0*b1.y; acc[0][6] += a0*b1.z; acc[0][7] += a0*b1.w;
        acc[1][0] += a1*b0.x; acc[1][1] += a1*b0.y; acc[1][2] += a1*b0.z; acc[1][3] += a1*b0.w;
        acc[1][4] += a1*b1.x; acc[1][5] += a1*b1.y; acc[1][6] += a1*b1.z; acc[1][7] += a1*b1.w;
      }
    }
  }
  #pragma unroll
  for (int i = 0; i < 2; ++i) {
    const int r = r0 + rg*2 + i;
    #pragma unroll
    for (int j = 0; j < 8; ++j) out[r*128 + cg*8 + j] = acc[i][j];
  }
}

// ---------------------------------------------------------------------------
// Dense P @ xWh, split-K=8 into partial buffers. BM=64, BN=128, BK=32,
// 256 threads, thread tile 4x8.
__global__ __launch_bounds__(256) void k_pgemm(const float* __restrict__ P,
                                               const float* __restrict__ ws,
                                               float* __restrict__ zpart) {
  const int rbl = blockIdx.x;   // 64 row-blocks of 64
  const int kz  = blockIdx.y;   // 8 K-splits of 512
  const float* __restrict__ Xw = ws + XWH_OFF;

  __shared__ __align__(16) float Pt[64][33];
  __shared__ __align__(16) float Xt[32][132];
  const int t = threadIdx.x;
  const int rg = t >> 4, cg = t & 15;   // 16 x 4 rows, 16 x 8 cols
  const int r0 = rbl * 64;
  const int kbase = kz * 512;
  float acc[4][8];
  #pragma unroll
  for (int i = 0; i < 4; ++i)
    #pragma unroll
    for (int j = 0; j < 8; ++j) acc[i][j] = 0.f;

  for (int k0 = kbase; k0 < kbase + 512; k0 += 32) {
    __syncthreads();
    #pragma unroll
    for (int l = 0; l < 2; ++l) { // stage P: 64x32
      const int idx = t + l*256;
      const int row = idx >> 3, kq = idx & 7;
      const float4 pv = *(const float4*)&P[(size_t)(r0 + row)*NN + k0 + kq*4];
      Pt[row][kq*4+0] = pv.x; Pt[row][kq*4+1] = pv.y;
      Pt[row][kq*4+2] = pv.z; Pt[row][kq*4+3] = pv.w;
    }
    #pragma unroll
    for (int l = 0; l < 4; ++l) { // stage xWh: 32x128
      const int idx = t + l*256;
      const int kr = idx >> 5, c4 = idx & 31;
      const float4 xv = *(const float4*)&Xw[(k0 + kr)*128 + c4*4];
      Xt[kr][c4*4+0] = xv.x; Xt[kr][c4*4+1] = xv.y;
      Xt[kr][c4*4+2] = xv.z; Xt[kr][c4*4+3] = xv.w;
    }
    __syncthreads();
    #pragma unroll
    for (int k = 0; k < 32; ++k) {
      const float a0 = Pt[rg*4 + 0][k];
      const float a1 = Pt[rg*4 + 1][k];
      const float a2 = Pt[rg*4 + 2][k];
      const float a3 = Pt[rg*4 + 3][k];
      const float4 b0 = *(const float4*)&Xt[k][cg*8];
      const float4 b1 = *(const float4*)&Xt[k][cg*8 + 4];
      acc[0][0] += a0*b0.x; acc[0][1] += a0*b0.y; acc[0][2] += a0*b0.z; acc[0][3] += a0*b0.w;
      acc[0][4] += a0*b1.x; acc[0][5] += a0*b1.y; acc[0][6] += a0*b1.z; acc[0][7] += a0*b1.w;
      acc[1][0] += a1*b0.x; acc[1][1] += a1*b0.y; acc[1][2] += a1*b0.z; acc[1][3] += a1*b0.w;
      acc[1][4] += a1*b1.x; acc[1][5] += a1*b1.y; acc[1][6] += a1*b1.z; acc[1][7] += a1*b1.w;
      acc[2][0] += a2*b0.x; acc[2][1] += a2*b0.y; acc[2][2] += a2*b0.z; acc[2][3] += a2*b0.w;
      acc[2][4] += a2*b1.x; acc[2][5] += a2*b1.y; acc[2][6] += a2*b1.z; acc[2][7] += a2*b1.w;
      acc[3][0] += a3*b0.x; acc[3][1] += a3*b0.y; acc[3][2] += a3*b0.z; acc[3][3] += a3*b0.w;
      acc[3][4] += a3*b1.x; acc[3][5] += a3*b1.y; acc[3][6] += a3*b1.z; acc[3][7] += a3*b1.w;
    }
  }
  float* __restrict__ zp = zpart + (size_t)kz * NN * 128;
  #pragma unroll
  for (int i = 0; i < 4; ++i) {
    const int r = r0 + rg*4 + i;
    #pragma unroll
    for (int j = 0; j < 8; ++j) zp[r*128 + cg*8 + j] = acc[i][j];
  }
}

// ---------------------------------------------------------------------------
// Masked-softmax attention v2: same 4-wave interleaved-gather structure as
// k_spmm_emit. O[i,:] = (sum_j e_j * U[j,:]) / (sum_j e_j), skipping masked
// entries (exact: they underflow to 0 in the reference's softmax).
__global__ __launch_bounds__(256) void k_attn(
    const float* __restrict__ Ld, const float* __restrict__ Lu,
    float* __restrict__ ws, const unsigned short* __restrict__ idxbuf,
    const int* __restrict__ cntbuf) {
  const int row = blockIdx.x & (NN - 1);
  const int br  = blockIdx.x >> 12;
  const float* __restrict__ U = ws + (br ? US_OFF : UI_OFF);
  const float2* __restrict__ U2 = (const float2*)U;
  float* __restrict__ O = ws + (br ? OS_OFF : OI_OFF);
  const float s1 = ws[S_OFF + (br ? 2*NN : 0) + row];
  const float* __restrict__ s2a = ws + S_OFF + (br ? 3*NN : NN);
  const int cnt = cntbuf[br*NN + row];
  const int t = threadIdx.x;
  const int w = t >> 6, lane = t & 63;

  __shared__ int   jl[IDX_CAP];
  __shared__ float el[IDX_CAP];
  __shared__ float red[4][128];
  __shared__ float rsum[256];
  __shared__ float dsh[4];

  float acc0 = 0.f, acc1 = 0.f;
  if (cnt > 0 && cnt <= IDX_CAP) {
    const unsigned short* __restrict__ idx = idxbuf + (size_t)(br*NN + row) * IDX_CAP;
    float dpart = 0.f;
    for (int p = t; p < cnt; p += 256) {
      const int j = idx[p];
      const float sc = s1 + s2a[j];
      const float e = expf(sc >= 0.f ? sc : SLOPE * sc);
      jl[p] = j; el[p] = e; dpart += e;
    }
    rsum[t] = dpart;
    __syncthreads();
    if (t < 128) rsum[t] += rsum[t + 128];
    __syncthreads();
    if (t < 64) {
      float v = rsum[t] + rsum[t + 64];
      #pragma unroll
      for (int off = 32; off; off >>= 1) v += __shfl_down(v, off);
      if (t == 0) dsh[0] = v;
    }
    __syncthreads();
    const float den = dsh[0];
    // gather: wave w takes p = w, w+4, ...; unroll 4 -> stride 16
    int p = w;
    for (; p + 12 < cnt; p += 16) {
      const int j0 = jl[p], j1 = jl[p+4], j2 = jl[p+8], j3 = jl[p+12];
      const float e0 = el[p], e1 = el[p+4], e2 = el[p+8], e3 = el[p+12];
      const float2 g0 = U2[j0*64 + lane];
      const float2 g1 = U2[j1*64 + lane];
      const float2 g2 = U2[j2*64 + lane];
      const float2 g3 = U2[j3*64 + lane];
      acc0 += e0*g0.x; acc1 += e0*g0.y;
      acc0 += e1*g1.x; acc1 += e1*g1.y;
      acc0 += e2*g2.x; acc1 += e2*g2.y;
      acc0 += e3*g3.x; acc1 += e3*g3.y;
    }
    for (; p < cnt; p += 4) {
      const int j = jl[p]; const float e = el[p];
      const float2 g = U2[j*64 + lane];
      acc0 += e*g.x; acc1 += e*g.y;
    }
    red[w][lane*2]     = acc0;
    red[w][lane*2 + 1] = acc1;
    __syncthreads();
    if (t < 128)
      O[row*128 + t] = (red[0][t] + red[1][t] + red[2][t] + red[3][t]) / den;
  } else if (cnt == 0) {
    // all-masked row -> reference softmax is uniform 1/N (never hit at 5%)
    for (int j = w*1024; j < (w+1)*1024; ++j) {
      const float2 g = U2[j*64 + lane];
      acc0 += g.x; acc1 += g.y;
    }
    red[w][lane*2]     = acc0;
    red[w][lane*2 + 1] = acc1;
    __syncthreads();
    if (t < 128)
      O[row*128 + t] = (red[0][t] + red[1][t] + red[2][t] + red[3][t]) * (1.f / NN);
  } else {
    // overflowed index cap: dense rescan, wave quarter of the row
    const float* __restrict__ Lrow = (br ? Lu : Ld) + (size_t)row * NN;
    float dp = 0.f;
    for (int j = w*1024; j < (w+1)*1024; ++j) {
      const float v = Lrow[j];
      if (v != 0.f) {
        const float sc = s1 + s2a[j];
        const float e = expf(sc >= 0.f ? sc : SLOPE * sc);
        const float2 g = U2[j*64 + lane];
        acc0 += e*g.x; acc1 += e*g.y;
        dp += e;
      }
    }
    if (lane == 0) dsh[w] = dp;
    red[w][lane*2]     = acc0;
    red[w][lane*2 + 1] = acc1;
    __syncthreads();
    const float den = dsh[0] + dsh[1] + dsh[2] + dsh[3];
    if (t < 128)
      O[row*128 + t] = (red[0][t] + red[1][t] + red[2][t] + red[3][t]) / den;
  }
}

// ---------------------------------------------------------------------------
// z = O_irr + O_sol + sum_k zpart[k] + b_total
__global__ __launch_bounds__(256) void k_combine(const float* __restrict__ ws,
                                                 float* __restrict__ z) {
  const int i = blockIdx.x * 256 + threadIdx.x;
  const int col = i & 127;
  float acc = ws[BT_OFF + col] + ws[OI_OFF + i] + ws[OS_OFF + i];
  #pragma unroll
  for (int kz = 0; kz < 8; ++kz) acc += ws[ZP_OFF + kz*NN*128 + i];
  z[i] = acc;
}

// ---------------------------------------------------------------------------
extern "C" void kernel_launch(void* const* d_in, const int* in_sizes, int n_in,
                              void* d_out, int out_size, void* d_ws, size_t ws_size,
                              hipStream_t stream) {
  const float* x       = (const float*)d_in[0];
  const float* Lu      = (const float*)d_in[1];
  const float* Ld      = (const float*)d_in[2];
  const float* P       = (const float*)d_in[3];
  const float* Wi_w    = (const float*)d_in[4];
  const float* Wi_b    = (const float*)d_in[5];
  const float* Ws_w    = (const float*)d_in[6];
  const float* Ws_b    = (const float*)d_in[7];
  const float* Wh_w    = (const float*)d_in[8];
  const float* Wh_b    = (const float*)d_in[9];
  const float* att_irr = (const float*)d_in[10];
  const float* att_sol = (const float*)d_in[11];
  float* z  = (float*)d_out;
  float* ws = (float*)d_ws;
  unsigned short* idxbuf = (unsigned short*)((char*)d_ws + IDX_BYTE_OFF);
  int*            cntbuf = (int*)((char*)d_ws + CNT_BYTE_OFF);

  k_prep<<<1, 128, 0, stream>>>(Wi_w, Wi_b, Ws_w, Ws_b, Wh_b, att_irr, att_sol, ws);
  k_scores<<<1024, 256, 0, stream>>>(x, ws);
  k_spmm_emit<<<2 * NN, 256, 0, stream>>>(Ld, Lu, x, ws, idxbuf, cntbuf);
  {
    dim3 g(128, 3);
    k_ugemm<<<g, 256, 0, stream>>>(x, Wi_w, Ws_w, Wh_w, ws);
  }
  {
    dim3 g(64, 8);
    k_pgemm<<<g, 256, 0, stream>>>(P, ws, ws + ZP_OFF);
  }
  k_attn<<<2 * NN, 256, 0, stream>>>(Ld, Lu, ws, idxbuf, cntbuf);
  k_combine<<<NN * 128 / 256, 256, 0, stream>>>(ws, z);
}